// Round 16
// baseline (497.734 us; speedup 1.0000x reference)
//
#include <hip/hip_runtime.h>
#include <math.h>

// B=64, L=512, C=64, E=64, F=257, PRED=512, H1=1024, H2=3072
// ---- workspace layout (f32 units), peak 17,047,552 = 68.19 MB (proven) ----
#define U_HBF   0            // bf16 [4096][1024] = 2097152 f32 units (h born bf16)
#define U_FC2P  0            // f32 4 x [512*4096] partials over dead hbf (fc2 stage)
#define U_MFT   4194304      // [4096][512]             -> 6291456
#define U_XRE   6291456      // [64][257][64]           -> 7344128
#define U_XIM   7344128      //                         -> 8396800
#define U_KEEPI 8396800      // int[4096*32]            -> 8527872
#define U_KEEPW 8527872      //                         -> 8658944
#define U_XFILT 8658944      // [64][512][64]           -> 10756096
#define U_NORM  10756096     // [64][512][64]           -> 12853248
#define U_Q     6291456      // bf16 [64][512][64] over dead xre/xim
#define U_K     12853248     // bf16 [64][512][64]
#define U_V     14950400     // bf16 V^T [64][64][512]           (peak 17047552)
#define U_HIDBF 8388608      // bf16 [4096][3072] = 6291456 u -> 14680064
#define U_W1BF  14680064     // bf16 [3072][1024] = 1572864 u -> 16252928
#define U_W2BF  16252928     // bf16 [512][3072]  =  786432 u -> 17039360
// DFT partial slices (z=1..3), live only dft_split..dft_reduce:
#define U_PART  8658944      // 3 x 2105344 floats -> ends 14974976

#define TWO_PI_OVER_512 0.012271846303085129

typedef __attribute__((ext_vector_type(8))) short short8;
typedef __attribute__((ext_vector_type(4))) float floatx4;

__device__ inline unsigned short f2bf(float f) {
    union { unsigned int i; float f; } x; x.f = f;
    unsigned int r = x.i + 0x7fff + ((x.i >> 16) & 1);
    return (unsigned short)(r >> 16);
}

// ===== 1a. split DFT (EXACT round-14 scalar version — proven) =====
__global__ __launch_bounds__(256) void dft_split(const float* __restrict__ x,
                                                 float* __restrict__ xre,
                                                 float* __restrict__ xim,
                                                 float* __restrict__ part) {
    __shared__ float xs[64 * 64];
    __shared__ float ct[512], st[512];
    int tid = threadIdx.x;
    int b = blockIdx.y;
    int f0 = blockIdx.x * 64;
    int z = blockIdx.z;
    for (int i = tid; i < 512; i += 256) {
        float s, c; sincosf((float)((double)i * TWO_PI_OVER_512), &s, &c);
        ct[i] = c; st[i] = s;
    }
    int c2 = (tid & 31) * 2;
    int fg = tid >> 5;
    int fb = f0 + fg * 8;
    float2 ar[8], ai[8];
    #pragma unroll
    for (int i = 0; i < 8; ++i) { ar[i] = make_float2(0.f, 0.f); ai[i] = make_float2(0.f, 0.f); }
    for (int sub = 0; sub < 2; ++sub) {
        int t0 = z * 128 + sub * 64;
        __syncthreads();
        for (int i = tid; i < 4096; i += 256)
            xs[i] = x[(size_t)(b * 512 + t0) * 64 + i];
        __syncthreads();
        for (int tt = 0; tt < 64; ++tt) {
            float2 xv = *(float2*)&xs[tt * 64 + c2];
            int t = t0 + tt;
            int idx = (fb * t) & 511;
            #pragma unroll
            for (int i = 0; i < 8; ++i) {
                float cv = ct[idx], sv = st[idx];
                ar[i].x += xv.x * cv; ar[i].y += xv.y * cv;
                ai[i].x -= xv.x * sv; ai[i].y -= xv.y * sv;
                idx = (idx + t) & 511;
            }
        }
    }
    float* dre = (z == 0) ? xre : (part + (size_t)(z - 1) * 2105344);
    float* dim_ = (z == 0) ? xim : (part + (size_t)(z - 1) * 2105344 + 1052672);
    #pragma unroll
    for (int i = 0; i < 8; ++i) {
        int f = fb + i;
        if (f < 257) {
            *(float2*)&dre[((size_t)(b * 257) + f) * 64 + c2] = ar[i];
            *(float2*)&dim_[((size_t)(b * 257) + f) * 64 + c2] = ai[i];
        }
    }
}

// ===== 1b. reduce partials (proven round 12) =====
__global__ __launch_bounds__(256) void dft_reduce(float* __restrict__ xreflat,
                                                  const float* __restrict__ part) {
    int i = blockIdx.x * 256 + threadIdx.x;
    if (i < 526336) {
        float4 a  = *(float4*)&xreflat[(size_t)i * 4];
        float4 p0 = *(const float4*)&part[(size_t)i * 4];
        float4 p1 = *(const float4*)&part[2105344 + (size_t)i * 4];
        float4 p2 = *(const float4*)&part[4210688 + (size_t)i * 4];
        a.x += p0.x + p1.x + p2.x;
        a.y += p0.y + p1.y + p2.y;
        a.z += p0.z + p1.z + p2.z;
        a.w += p0.w + p1.w + p2.w;
        *(float4*)&xreflat[(size_t)i * 4] = a;
    }
}

// ===== 2. block-per-row LDS-tree top-k (proven round 9) =====
__global__ __launch_bounds__(256) void topk_lds(const float* __restrict__ xre,
                                                const float* __restrict__ xim,
                                                int* __restrict__ keepi,
                                                float* __restrict__ keepw,
                                                const int* __restrict__ kptr) {
    __shared__ float vals[320];
    __shared__ float tv[256];
    __shared__ int   ti[256];
    int tid = threadIdx.x;
    int bc = blockIdx.x;
    int b = bc >> 6, c = bc & 63;
    int kk = *kptr; if (kk > 32) kk = 32;
    for (int f = tid; f < 320; f += 256) {
        if (f < 257) {
            size_t a = ((size_t)(b * 257) + f) * 64 + c;
            float re = xre[a], im = xim[a];
            vals[f] = sqrtf(re * re + im * im);
        } else vals[f] = -1.f;
    }
    __syncthreads();
    for (int j = 0; j < kk; ++j) {
        float v0 = vals[tid];
        int   i0 = tid;
        if (tid < 64) {
            float v1 = vals[tid + 256];
            if (v1 > v0) { v0 = v1; i0 = tid + 256; }
        }
        tv[tid] = v0; ti[tid] = i0;
        __syncthreads();
        for (int s = 128; s > 0; s >>= 1) {
            if (tid < s) {
                float ov = tv[tid + s]; int oi = ti[tid + s];
                if (ov > tv[tid] || (ov == tv[tid] && oi < ti[tid])) { tv[tid] = ov; ti[tid] = oi; }
            }
            __syncthreads();
        }
        if (tid == 0) {
            int bf = ti[0];
            keepi[bc * 32 + j] = bf;
            keepw[bc * 32 + j] = (bf == 0 || bf == 256) ? (1.f / 512.f) : (2.f / 512.f);
            vals[bf] = -1.f;
        }
        __syncthreads();
    }
}

// ===== 3. fused x_filt (proven round 7; xt-half written bf16 into hbf) =====
__global__ __launch_bounds__(256) void xfilt_fused(const float* __restrict__ x,
                                                   const float* __restrict__ xre,
                                                   const float* __restrict__ xim,
                                                   const int* __restrict__ keepi,
                                                   const float* __restrict__ keepw,
                                                   float* __restrict__ xfilt,
                                                   float* __restrict__ norm,
                                                   float* __restrict__ mft,
                                                   unsigned short* __restrict__ hbf,
                                                   const int* __restrict__ kptr) {
    __shared__ float ct[512], st[512];
    __shared__ int   kf[64 * 33];
    __shared__ float kre[64 * 33], kim[64 * 33];
    __shared__ float xs[64 * 65];
    __shared__ float ft[64 * 65];
    int tid = threadIdx.x;
    int b = blockIdx.y;
    int t0 = blockIdx.x * 64;
    int kk = *kptr; if (kk > 32) kk = 32;
    for (int i = tid; i < 512; i += 256) {
        float s, c; sincosf((float)((double)i * TWO_PI_OVER_512), &s, &c);
        ct[i] = c; st[i] = s;
    }
    for (int i = tid; i < 4096; i += 256) {
        int tl = i >> 6, c = i & 63;
        xs[tl * 65 + c] = x[((size_t)(b * 512) + t0 + tl) * 64 + c];
    }
    for (int e = tid; e < 64 * kk; e += 256) {
        int c = e / kk, j = e - c * kk;
        int bc = b * 64 + c;
        int f = keepi[bc * 32 + j];
        float w = keepw[bc * 32 + j];
        size_t a = ((size_t)(b * 257) + f) * 64 + c;
        kf[c * 33 + j]  = f;
        kre[c * 33 + j] = w * xre[a];
        kim[c * 33 + j] = w * xim[a];
    }
    __syncthreads();
    int l = tid & 63, w = tid >> 6;
    int t = t0 + l;
    for (int ci = 0; ci < 16; ++ci) {
        int c = w * 16 + ci;
        float acc = 0.f;
        for (int j = 0; j < kk; ++j) {
            int f = kf[c * 33 + j];
            int idx = (f * t) & 511;
            acc += kre[c * 33 + j] * ct[idx] - kim[c * 33 + j] * st[idx];
        }
        ft[c * 65 + l] = acc;
    }
    __syncthreads();
    for (int i = tid; i < 4096; i += 256) {
        int tl = i >> 6, c = i & 63;
        float v = ft[c * 65 + tl];
        size_t a = ((size_t)(b * 512) + t0 + tl) * 64 + c;
        xfilt[a] = v;
        norm[a]  = xs[tl * 65 + c] - v;
    }
    for (int i = tid; i < 4096; i += 256) {
        int cr = i >> 6, tl = i & 63;
        mft[((size_t)(b * 64) + cr) * 512 + t0 + tl] = ft[cr * 65 + tl];
        hbf[((size_t)(b * 64) + cr) * 1024 + 512 + t0 + tl] = f2bf(xs[tl * 65 + cr]);
    }
}

// ===== 4. QKV as tiled GEMM (proven round 11) =====
__global__ __launch_bounds__(256) void qkv_gemm(const float* __restrict__ xfilt,
                                                const float* __restrict__ norm,
                                                const float* __restrict__ w,
                                                const float* __restrict__ bias,
                                                unsigned short* __restrict__ q,
                                                unsigned short* __restrict__ kmat,
                                                unsigned short* __restrict__ vt) {
    __shared__ float As[32 * 64];
    __shared__ float Bs[32 * 64];
    __shared__ unsigned short Cs[64 * 65];
    int tid = threadIdx.x;
    int tx = tid & 15, ty = tid >> 4;
    int grp = blockIdx.x;
    int m0 = blockIdx.y * 64;
    int n0 = grp * 64;
    const float* A = (grp == 0) ? xfilt : norm;
    float acc[4][4] = {};
    for (int k0 = 0; k0 < 64; k0 += 32) {
        __syncthreads();
        #pragma unroll
        for (int s = 0; s < 2; ++s) {
            int i4 = tid + s * 256;
            int row = i4 >> 3, kq = i4 & 7;
            float4 a4 = *(const float4*)&A[(size_t)(m0 + row) * 64 + k0 + kq * 4];
            float4 w4 = *(const float4*)&w[(size_t)(n0 + row) * 64 + k0 + kq * 4];
            int kb = kq * 4;
            As[(kb + 0) * 64 + row] = a4.x; As[(kb + 1) * 64 + row] = a4.y;
            As[(kb + 2) * 64 + row] = a4.z; As[(kb + 3) * 64 + row] = a4.w;
            Bs[(kb + 0) * 64 + row] = w4.x; Bs[(kb + 1) * 64 + row] = w4.y;
            Bs[(kb + 2) * 64 + row] = w4.z; Bs[(kb + 3) * 64 + row] = w4.w;
        }
        __syncthreads();
        #pragma unroll
        for (int kk = 0; kk < 32; ++kk) {
            float4 a4 = *(const float4*)&As[kk * 64 + (ty << 2)];
            float4 b4 = *(const float4*)&Bs[kk * 64 + (tx << 2)];
            #pragma unroll
            for (int i = 0; i < 4; ++i)
                #pragma unroll
                for (int j = 0; j < 4; ++j)
                    acc[i][j] += (&a4.x)[i] * (&b4.x)[j];
        }
    }
    int row0 = ty * 4, col0 = tx * 4;
    float4 bb = *(const float4*)&bias[n0 + col0];
    #pragma unroll
    for (int i = 0; i < 4; ++i) {
        float v0 = acc[i][0] + bb.x, v1 = acc[i][1] + bb.y;
        float v2 = acc[i][2] + bb.z, v3 = acc[i][3] + bb.w;
        ushort4 o;
        o.x = f2bf(v0); o.y = f2bf(v1); o.z = f2bf(v2); o.w = f2bf(v3);
        if (grp == 0) {
            *(ushort4*)&q[(size_t)(m0 + row0 + i) * 64 + col0] = o;
        } else if (grp == 1) {
            *(ushort4*)&kmat[(size_t)(m0 + row0 + i) * 64 + col0] = o;
        } else {
            Cs[(row0 + i) * 65 + col0 + 0] = o.x;
            Cs[(row0 + i) * 65 + col0 + 1] = o.y;
            Cs[(row0 + i) * 65 + col0 + 2] = o.z;
            Cs[(row0 + i) * 65 + col0 + 3] = o.w;
        }
    }
    if (grp == 2) {
        __syncthreads();
        int b = m0 >> 9, t0 = m0 & 511;
        for (int i2 = tid; i2 < 4096; i2 += 256) {
            int e = i2 >> 6, tl = i2 & 63;
            vt[((size_t)(b * 64) + e) * 512 + t0 + tl] = Cs[tl * 65 + e];
        }
    }
}

// ===== 5. MFMA attention + out-proj, low-LDS (proven rounds 13/14) =====
__global__ __launch_bounds__(256) void attn_mfma(const unsigned short* __restrict__ qbf,
                                                 const unsigned short* __restrict__ kbf,
                                                 const unsigned short* __restrict__ vtbf,
                                                 const float* __restrict__ ow,
                                                 const float* __restrict__ ob,
                                                 float* __restrict__ out) {
    __shared__ unsigned short Qs[64 * 72];
    __shared__ unsigned short KVs[64 * 72];
    __shared__ unsigned short Pp[4 * 16 * 72];
    int tid = threadIdx.x;
    int l = tid & 63, w = tid >> 6;
    int q = l >> 4, cl = l & 15;
    int b = blockIdx.y, i0 = blockIdx.x * 64;

    for (int i = tid; i < 1024; i += 256) {
        int r = i >> 4, e4 = (i & 15) * 4;
        *(ushort4*)&Qs[r * 72 + e4] = *(const ushort4*)&qbf[((size_t)(b * 512) + i0 + r) * 64 + e4];
    }
    __syncthreads();
    short8 aq0 = *(short8*)&Qs[(w * 16 + cl) * 72 + q * 8];
    short8 aq1 = *(short8*)&Qs[(w * 16 + cl) * 72 + 32 + q * 8];

    floatx4 s[32];
    #pragma unroll
    for (int f = 0; f < 32; ++f) s[f] = (floatx4){0.f, 0.f, 0.f, 0.f};

    #pragma unroll
    for (int ch = 0; ch < 8; ++ch) {
        __syncthreads();
        for (int i = tid; i < 1024; i += 256) {
            int jj = i >> 4, e4 = (i & 15) * 4;
            *(ushort4*)&KVs[jj * 72 + e4] =
                *(const ushort4*)&kbf[((size_t)(b * 512) + ch * 64 + jj) * 64 + e4];
        }
        __syncthreads();
        #pragma unroll
        for (int jt = 0; jt < 4; ++jt) {
            short8 b0 = *(short8*)&KVs[(jt * 16 + cl) * 72 + q * 8];
            short8 b1 = *(short8*)&KVs[(jt * 16 + cl) * 72 + 32 + q * 8];
            s[ch * 4 + jt] = __builtin_amdgcn_mfma_f32_16x16x32_bf16(aq0, b0, s[ch * 4 + jt], 0, 0, 0);
            s[ch * 4 + jt] = __builtin_amdgcn_mfma_f32_16x16x32_bf16(aq1, b1, s[ch * 4 + jt], 0, 0, 0);
        }
    }

    float invl[4];
    #pragma unroll
    for (int r = 0; r < 4; ++r) {
        float m = -1e30f;
        #pragma unroll
        for (int f = 0; f < 32; ++f) m = fmaxf(m, s[f][r]);
        m = fmaxf(m, __shfl_xor(m, 1)); m = fmaxf(m, __shfl_xor(m, 2));
        m = fmaxf(m, __shfl_xor(m, 4)); m = fmaxf(m, __shfl_xor(m, 8));
        float sum = 0.f;
        #pragma unroll
        for (int f = 0; f < 32; ++f) {
            float p = expf((s[f][r] - m) * 0.125f);
            s[f][r] = p; sum += p;
        }
        sum += __shfl_xor(sum, 1); sum += __shfl_xor(sum, 2);
        sum += __shfl_xor(sum, 4); sum += __shfl_xor(sum, 8);
        invl[r] = 1.f / sum;
    }

    floatx4 o4[4];
    #pragma unroll
    for (int nt = 0; nt < 4; ++nt) o4[nt] = (floatx4){0.f, 0.f, 0.f, 0.f};
    #pragma unroll
    for (int ch = 0; ch < 8; ++ch) {
        #pragma unroll
        for (int jt = 0; jt < 4; ++jt)
            #pragma unroll
            for (int r = 0; r < 4; ++r)
                Pp[w * 1152 + (q * 4 + r) * 72 + jt * 16 + cl] = f2bf(s[ch * 4 + jt][r]);
        __syncthreads();
        for (int i = tid; i < 1024; i += 256) {
            int e = i >> 4, j4 = (i & 15) * 4;
            *(ushort4*)&KVs[e * 72 + j4] =
                *(const ushort4*)&vtbf[((size_t)(b * 64) + e) * 512 + ch * 64 + j4];
        }
        __syncthreads();
        #pragma unroll
        for (int ks = 0; ks < 2; ++ks) {
            short8 ap = *(short8*)&Pp[w * 1152 + cl * 72 + ks * 32 + q * 8];
            #pragma unroll
            for (int nt = 0; nt < 4; ++nt) {
                short8 bv = *(short8*)&KVs[(nt * 16 + cl) * 72 + ks * 32 + q * 8];
                o4[nt] = __builtin_amdgcn_mfma_f32_16x16x32_bf16(ap, bv, o4[nt], 0, 0, 0);
            }
        }
    }

    #pragma unroll
    for (int nt = 0; nt < 4; ++nt)
        #pragma unroll
        for (int r = 0; r < 4; ++r)
            Qs[(w * 16 + q * 4 + r) * 72 + nt * 16 + cl] = f2bf(o4[nt][r] * invl[r]);
    __syncthreads();
    for (int i = tid; i < 1024; i += 256) {
        int o = i >> 4, e4 = (i & 15) * 4;
        float4 v = *(const float4*)&ow[o * 64 + e4];
        ushort4 u; u.x = f2bf(v.x); u.y = f2bf(v.y); u.z = f2bf(v.z); u.w = f2bf(v.w);
        *(ushort4*)&KVs[o * 72 + e4] = u;
    }
    __syncthreads();
    floatx4 acc2[4];
    #pragma unroll
    for (int nt = 0; nt < 4; ++nt) acc2[nt] = (floatx4){0.f, 0.f, 0.f, 0.f};
    #pragma unroll
    for (int ks = 0; ks < 2; ++ks) {
        short8 ao = *(short8*)&Qs[(w * 16 + cl) * 72 + ks * 32 + q * 8];
        #pragma unroll
        for (int nt = 0; nt < 4; ++nt) {
            short8 bo = *(short8*)&KVs[(nt * 16 + cl) * 72 + ks * 32 + q * 8];
            acc2[nt] = __builtin_amdgcn_mfma_f32_16x16x32_bf16(ao, bo, acc2[nt], 0, 0, 0);
        }
    }
    #pragma unroll
    for (int nt = 0; nt < 4; ++nt) {
        float bb = ob[nt * 16 + cl];
        #pragma unroll
        for (int r = 0; r < 4; ++r)
            out[((size_t)(b * 512) + i0 + w * 16 + q * 4 + r) * 64 + nt * 16 + cl] = acc2[nt][r] + bb;
    }
}

// ===== 6. tiled fp32 GEMM, FAN epilogues -> bf16 hbf (proven round 13) =====
template<int EPI>
__global__ __launch_bounds__(256) void gemm_k(const float* __restrict__ A,
                                              const float* __restrict__ W,
                                              const float* __restrict__ bias,
                                              unsigned short* __restrict__ C,
                                              int K,
                                              const float* __restrict__ gate) {
    __shared__ float As[32 * 64];
    __shared__ float Bs[32 * 64];
    int tid = threadIdx.x;
    int tx = tid & 15, ty = tid >> 4;
    int m0 = blockIdx.y * 64, n0 = blockIdx.x * 64;
    float acc[4][4] = {};
    for (int k0 = 0; k0 < K; k0 += 32) {
        __syncthreads();
        #pragma unroll
        for (int s = 0; s < 2; ++s) {
            int i4 = tid + s * 256;
            int row = i4 >> 3, kq = i4 & 7;
            float4 a4 = *(const float4*)&A[(size_t)(m0 + row) * K + k0 + kq * 4];
            float4 w4 = *(const float4*)&W[(size_t)(n0 + row) * K + k0 + kq * 4];
            int kb = kq * 4;
            As[(kb + 0) * 64 + row] = a4.x; As[(kb + 1) * 64 + row] = a4.y;
            As[(kb + 2) * 64 + row] = a4.z; As[(kb + 3) * 64 + row] = a4.w;
            Bs[(kb + 0) * 64 + row] = w4.x; Bs[(kb + 1) * 64 + row] = w4.y;
            Bs[(kb + 2) * 64 + row] = w4.z; Bs[(kb + 3) * 64 + row] = w4.w;
        }
        __syncthreads();
        #pragma unroll
        for (int kk = 0; kk < 32; ++kk) {
            float4 a4 = *(const float4*)&As[kk * 64 + (ty << 2)];
            float4 b4 = *(const float4*)&Bs[kk * 64 + (tx << 2)];
            #pragma unroll
            for (int i = 0; i < 4; ++i)
                #pragma unroll
                for (int j = 0; j < 4; ++j)
                    acc[i][j] += (&a4.x)[i] * (&b4.x)[j];
        }
    }
    int row0 = m0 + ty * 4, col0 = n0 + tx * 4;
    float4 bb = *(const float4*)&bias[col0];
    float gt = 1.f / (1.f + expf(-gate[0]));
    #pragma unroll
    for (int i = 0; i < 4; ++i) {
        int row = row0 + i;
        float v0 = acc[i][0] + bb.x, v1 = acc[i][1] + bb.y;
        float v2 = acc[i][2] + bb.z, v3 = acc[i][3] + bb.w;
        if (EPI == 2) {
            ushort4 co, si;
            co.x = f2bf(gt * cosf(v0)); co.y = f2bf(gt * cosf(v1));
            co.z = f2bf(gt * cosf(v2)); co.w = f2bf(gt * cosf(v3));
            si.x = f2bf(gt * sinf(v0)); si.y = f2bf(gt * sinf(v1));
            si.z = f2bf(gt * sinf(v2)); si.w = f2bf(gt * sinf(v3));
            *(ushort4*)&C[(size_t)row * 1024 + col0] = co;
            *(ushort4*)&C[(size_t)row * 1024 + 128 + col0] = si;
        } else if (EPI == 3) {
            float ig = 1.f - gt;
            ushort4 o;
            o.x = f2bf(ig * 0.5f * v0 * (1.f + erff(v0 * 0.70710678118f)));
            o.y = f2bf(ig * 0.5f * v1 * (1.f + erff(v1 * 0.70710678118f)));
            o.z = f2bf(ig * 0.5f * v2 * (1.f + erff(v2 * 0.70710678118f)));
            o.w = f2bf(ig * 0.5f * v3 * (1.f + erff(v3 * 0.70710678118f)));
            *(ushort4*)&C[(size_t)row * 1024 + 256 + col0] = o;
        }
    }
}

// ===== 7. cast f32 -> bf16 (weights only) =====
__global__ __launch_bounds__(256) void cast_bf16(const float* __restrict__ in,
                                                 unsigned short* __restrict__ out, int n4) {
    int i = blockIdx.x * 256 + threadIdx.x;
    if (i < n4) {
        float4 v = *(const float4*)&in[(size_t)i * 4];
        ushort4 o;
        o.x = f2bf(v.x); o.y = f2bf(v.y); o.z = f2bf(v.z); o.w = f2bf(v.w);
        *(ushort4*)&out[(size_t)i * 4] = o;
    }
}

// ===== 8. bf16 MFMA GEMM (proven round 6) — fc1 =====
__global__ __launch_bounds__(256) void gemm_mfma1(const unsigned short* __restrict__ A,
                                                  const unsigned short* __restrict__ B,
                                                  const float* __restrict__ bias,
                                                  unsigned short* __restrict__ Cb,
                                                  int M, int N, int K) {
    __shared__ unsigned short As[8192];
    __shared__ unsigned short Bs[8192];
    int tid = threadIdx.x;
    int l = tid & 63, w = tid >> 6;
    int q = l >> 4, cl = l & 15;
    int wm = w >> 1, wn = w & 1;
    int m0 = blockIdx.y * 128, n0 = blockIdx.x * 128;
    floatx4 acc[4][4];
    #pragma unroll
    for (int i = 0; i < 4; ++i)
        #pragma unroll
        for (int j = 0; j < 4; ++j)
            acc[i][j] = (floatx4){0.f, 0.f, 0.f, 0.f};

    for (int k0 = 0; k0 < K; k0 += 64) {
        __syncthreads();
        #pragma unroll
        for (int ci = 0; ci < 8; ++ci) {
            int cid = w * 8 + ci;
            int isB = cid >> 4;
            int c = cid & 15;
            int cq = c >> 3, cks = (c >> 2) & 1, cf = c & 3;
            int row = cq * 64 + cf * 16 + cl;
            int col = k0 + cks * 32 + q * 8;
            const unsigned short* gp = isB ? (B + (size_t)(n0 + row) * K + col)
                                           : (A + (size_t)(m0 + row) * K + col);
            unsigned short* lp = (isB ? Bs : As) + c * 512;
            __builtin_amdgcn_global_load_lds((const __attribute__((address_space(1))) void*)gp,
                                             (__attribute__((address_space(3))) void*)lp,
                                             16, 0, 0);
        }
        __syncthreads();
        #pragma unroll
        for (int ks = 0; ks < 2; ++ks) {
            short8 af[4], bg[4];
            #pragma unroll
            for (int f = 0; f < 4; ++f) {
                af[f] = *(short8*)&As[(wm * 8 + ks * 4 + f) * 512 + l * 8];
                bg[f] = *(short8*)&Bs[(wn * 8 + ks * 4 + f) * 512 + l * 8];
            }
            #pragma unroll
            for (int i = 0; i < 4; ++i)
                #pragma unroll
                for (int j = 0; j < 4; ++j)
                    acc[i][j] = __builtin_amdgcn_mfma_f32_16x16x32_bf16(af[i], bg[j], acc[i][j], 0, 0, 0);
        }
    }

    #pragma unroll
    for (int j = 0; j < 4; ++j) {
        int col = n0 + wn * 64 + j * 16 + cl;
        float bb = bias[col];
        #pragma unroll
        for (int i = 0; i < 4; ++i) {
            int rowb = m0 + wm * 64 + i * 16 + q * 4;
            #pragma unroll
            for (int r = 0; r < 4; ++r) {
                float v = acc[i][j][r] + bb;
                Cb[(size_t)(rowb + r) * N + col] = f2bf(fmaxf(v, 0.f));
            }
        }
    }
}

// ===== 9. fc2 split-K (proven round 14) =====
__global__ __launch_bounds__(256) void gemm_fc2_split(const unsigned short* __restrict__ A,
                                                      const unsigned short* __restrict__ B,
                                                      float* __restrict__ part,
                                                      int K) {
    __shared__ unsigned short As[8192];
    __shared__ unsigned short Bs[8192];
    int tid = threadIdx.x;
    int l = tid & 63, w = tid >> 6;
    int q = l >> 4, cl = l & 15;
    int wm = w >> 1, wn = w & 1;
    int m0 = blockIdx.y * 128, n0 = blockIdx.x * 128;
    int kbeg = blockIdx.z * 768;
    floatx4 acc[4][4];
    #pragma unroll
    for (int i = 0; i < 4; ++i)
        #pragma unroll
        for (int j = 0; j < 4; ++j)
            acc[i][j] = (floatx4){0.f, 0.f, 0.f, 0.f};

    for (int k0 = kbeg; k0 < kbeg + 768; k0 += 64) {
        __syncthreads();
        #pragma unroll
        for (int ci = 0; ci < 8; ++ci) {
            int cid = w * 8 + ci;
            int isB = cid >> 4;
            int c = cid & 15;
            int cq = c >> 3, cks = (c >> 2) & 1, cf = c & 3;
            int row = cq * 64 + cf * 16 + cl;
            int col = k0 + cks * 32 + q * 8;
            const unsigned short* gp = isB ? (B + (size_t)(n0 + row) * K + col)
                                           : (A + (size_t)(m0 + row) * K + col);
            unsigned short* lp = (isB ? Bs : As) + c * 512;
            __builtin_amdgcn_global_load_lds((const __attribute__((address_space(1))) void*)gp,
                                             (__attribute__((address_space(3))) void*)lp,
                                             16, 0, 0);
        }
        __syncthreads();
        #pragma unroll
        for (int ks = 0; ks < 2; ++ks) {
            short8 af[4], bg[4];
            #pragma unroll
            for (int f = 0; f < 4; ++f) {
                af[f] = *(short8*)&As[(wm * 8 + ks * 4 + f) * 512 + l * 8];
                bg[f] = *(short8*)&Bs[(wn * 8 + ks * 4 + f) * 512 + l * 8];
            }
            #pragma unroll
            for (int i = 0; i < 4; ++i)
                #pragma unroll
                for (int j = 0; j < 4; ++j)
                    acc[i][j] = __builtin_amdgcn_mfma_f32_16x16x32_bf16(af[i], bg[j], acc[i][j], 0, 0, 0);
        }
    }

    float* Ob = part + (size_t)blockIdx.z * 2097152;
    int bidx = (n0 >> 6) + wn;
    #pragma unroll
    for (int i = 0; i < 4; ++i) {
        #pragma unroll
        for (int r = 0; r < 4; ++r) {
            int t = m0 + wm * 64 + i * 16 + q * 4 + r;
            #pragma unroll
            for (int j = 0; j < 4; ++j) {
                int c = j * 16 + cl;
                Ob[((size_t)bidx * 512 + t) * 64 + c] = acc[i][j][r];
            }
        }
    }
}

// ===== 10. fc2 reduce (proven round 14) =====
__global__ __launch_bounds__(256) void fc2_reduce(const float* __restrict__ part,
                                                  const float* __restrict__ bias,
                                                  float* __restrict__ out) {
    int i = blockIdx.x * 256 + threadIdx.x;
    if (i < 524288) {
        size_t e = (size_t)i * 4;
        int t = (int)((e >> 6) & 511);
        float bb = bias[t];
        float4 p0 = *(const float4*)&part[e];
        float4 p1 = *(const float4*)&part[2097152 + e];
        float4 p2 = *(const float4*)&part[4194304 + e];
        float4 p3 = *(const float4*)&part[6291456 + e];
        float4 o;
        o.x = p0.x + p1.x + p2.x + p3.x + bb;
        o.y = p0.y + p1.y + p2.y + p3.y + bb;
        o.z = p0.z + p1.z + p2.z + p3.z + bb;
        o.w = p0.w + p1.w + p2.w + p3.w + bb;
        *(float4*)&out[e] = o;
    }
}

extern "C" void kernel_launch(void* const* d_in, const int* in_sizes, int n_in,
                              void* d_out, int out_size, void* d_ws, size_t ws_size,
                              hipStream_t stream) {
    const float* x         = (const float*)d_in[0];
    const float* in_proj_w = (const float*)d_in[1];
    const float* in_proj_b = (const float*)d_in[2];
    const float* out_w     = (const float*)d_in[3];
    const float* out_b     = (const float*)d_in[4];
    const float* Wp        = (const float*)d_in[5];
    const float* bp        = (const float*)d_in[6];
    const float* Wg        = (const float*)d_in[7];
    const float* bg        = (const float*)d_in[8];
    const float* gate      = (const float*)d_in[9];
    const float* fc1_w     = (const float*)d_in[10];
    const float* fc1_b     = (const float*)d_in[11];
    const float* fc2_w     = (const float*)d_in[12];
    const float* fc2_b     = (const float*)d_in[13];
    const int*   kptr      = (const int*)d_in[14];
    float* ws  = (float*)d_ws;
    float* out = (float*)d_out;

    float* mft   = ws + U_MFT;
    float* xre   = ws + U_XRE;
    float* xim   = ws + U_XIM;
    int*   keepi = (int*)(ws + U_KEEPI);
    float* keepw = ws + U_KEEPW;
    float* xfilt = ws + U_XFILT;
    float* norm  = ws + U_NORM;
    float* part  = ws + U_PART;
    float* fc2p  = ws + U_FC2P;
    unsigned short* hbf   = (unsigned short*)(ws + U_HBF);
    unsigned short* qb    = (unsigned short*)(ws + U_Q);
    unsigned short* kb    = (unsigned short*)(ws + U_K);
    unsigned short* vtb   = (unsigned short*)(ws + U_V);
    unsigned short* hidbf = (unsigned short*)(ws + U_HIDBF);
    unsigned short* w1bf  = (unsigned short*)(ws + U_W1BF);
    unsigned short* w2bf  = (unsigned short*)(ws + U_W2BF);

    dft_split  <<<dim3(5, 64, 4), 256, 0, stream>>>(x, xre, xim, part);
    dft_reduce <<<dim3(2056),     256, 0, stream>>>(xre, part);
    topk_lds   <<<dim3(4096),     256, 0, stream>>>(xre, xim, keepi, keepw, kptr);
    xfilt_fused<<<dim3(8, 64),    256, 0, stream>>>(x, xre, xim, keepi, keepw, xfilt, norm, mft, hbf, kptr);
    qkv_gemm   <<<dim3(3, 512),   256, 0, stream>>>(xfilt, norm, in_proj_w, in_proj_b, qb, kb, vtb);
    attn_mfma  <<<dim3(8, 64),    256, 0, stream>>>(qb, kb, vtb, out_w, out_b, out);
    gemm_k<2>  <<<dim3(2, 64),    256, 0, stream>>>(mft, Wp, bp, hbf, 512, gate);
    gemm_k<3>  <<<dim3(4, 64),    256, 0, stream>>>(mft, Wg, bg, hbf, 512, gate);
    cast_bf16<<<3072, 256, 0, stream>>>(fc1_w, w1bf, 786432);
    cast_bf16<<<1536, 256, 0, stream>>>(fc2_w, w2bf, 393216);
    gemm_mfma1    <<<dim3(24, 32),   256, 0, stream>>>(hbf, w1bf, fc1_b, hidbf, 4096, 3072, 1024);
    gemm_fc2_split<<<dim3(32, 4, 4), 256, 0, stream>>>(w2bf, hidbf, fc2p, 3072);
    fc2_reduce    <<<dim3(2048),     256, 0, stream>>>(fc2p, fc2_b, out + 2097152);
}